// Round 5
// baseline (2370.548 us; speedup 1.0000x reference)
//
#include <hip/hip_runtime.h>
#include <math.h>

#define M_ROWS 2048
#define N_KEYS 65536
#define DKK 512
#define DVV 512
#define KTOP 32
#define NSPLIT 32
#define NRANGE (N_KEYS / NSPLIT)   // 2048
#define BM 64
#define BN 128
#define MBLKS (M_ROWS / BM)        // 32
#define NTILES (NRANGE / BN)       // 16
#define KSTEPS (DKK / 32)          // 16
#define CAP 12
#define CSTR 13

typedef _Float16 f16x8 __attribute__((ext_vector_type(8)));
typedef _Float16 f16x4v __attribute__((ext_vector_type(4)));
typedef float f32x4 __attribute__((ext_vector_type(4)));

// ===================== FAST PATH =====================

__device__ __forceinline__ void split4(const float4 v, float inv,
                                       _Float16* ph, _Float16* pl) {
  f16x4v h, l;
  float y;
  y = v.x * inv; h[0] = (_Float16)y; l[0] = (_Float16)(y - (float)h[0]);
  y = v.y * inv; h[1] = (_Float16)y; l[1] = (_Float16)(y - (float)h[1]);
  y = v.z * inv; h[2] = (_Float16)y; l[2] = (_Float16)(y - (float)h[2]);
  y = v.w * inv; h[3] = (_Float16)y; l[3] = (_Float16)(y - (float)h[3]);
  *(f16x4v*)ph = h; *(f16x4v*)pl = l;
}

__global__ void __launch_bounds__(256) norm_split_kernel(
    const float* __restrict__ q, const float* __restrict__ keys,
    _Float16* __restrict__ Qh, _Float16* __restrict__ Ql,
    _Float16* __restrict__ Kh, _Float16* __restrict__ Kl) {
  const int gw = (blockIdx.x * 256 + threadIdx.x) >> 6;
  const int lane = threadIdx.x & 63;
  const float* row; _Float16 *oh, *ol;
  if (gw < M_ROWS) {
    row = q + (size_t)gw * DKK; oh = Qh + (size_t)gw * DKK; ol = Ql + (size_t)gw * DKK;
  } else {
    const int n = gw - M_ROWS;
    if (n >= N_KEYS) return;
    row = keys + (size_t)n * DKK; oh = Kh + (size_t)n * DKK; ol = Kl + (size_t)n * DKK;
  }
  const float4 a = ((const float4*)row)[lane];
  const float4 b = ((const float4*)row)[lane + 64];
  float s = a.x*a.x + a.y*a.y + a.z*a.z + a.w*a.w
          + b.x*b.x + b.y*b.y + b.z*b.z + b.w*b.w;
#pragma unroll
  for (int off = 32; off; off >>= 1) s += __shfl_xor(s, off);
  const float inv = 1.0f / fmaxf(sqrtf(s), 1e-12f);
  split4(a, inv, oh + lane * 4,       ol + lane * 4);
  split4(b, inv, oh + 256 + lane * 4, ol + 256 + lane * 4);
}

__device__ __forceinline__ void insert32(float* tS, int* tI, float s, int idx) {
  const float ms = tS[31]; const int mi_ = tI[31];
  if (s < ms || (s == ms && idx > mi_)) return;
  int p = 0;
  while (p < KTOP && (tS[p] > s || (tS[p] == s && tI[p] < idx))) ++p;
  for (int qq = KTOP - 1; qq > p; --qq) { tS[qq] = tS[qq-1]; tI[qq] = tI[qq-1]; }
  tS[p] = s; tI[p] = idx;
}

// Stage one K-step: Ah/Al (64x32) + Kh/Kl (128x32) -> LDS, via global_load_lds
// width 16. LDS dest linear in tid; global SOURCE pre-swizzled (rule #21) so
// that ds_read at (row r, octet g) uses phys octet g ^ ((r>>1)&3).
#define STAGE(BUF, N0, KS) do {                                                \
  const size_t _ko = (size_t)(KS) * 32;                                        \
  const size_t _qa = qsrc + _ko;                                               \
  const size_t _ba = (size_t)(N0) * DKK + bsrc + _ko;                          \
  __builtin_amdgcn_global_load_lds((const __attribute__((address_space(1))) void*)(Qh + _qa), \
      (__attribute__((address_space(3))) void*)&stA[BUF][0][ldsA], 16, 0, 0);  \
  __builtin_amdgcn_global_load_lds((const __attribute__((address_space(1))) void*)(Ql + _qa), \
      (__attribute__((address_space(3))) void*)&stA[BUF][1][ldsA], 16, 0, 0);  \
  __builtin_amdgcn_global_load_lds((const __attribute__((address_space(1))) void*)(Kh + _ba), \
      (__attribute__((address_space(3))) void*)&stB[BUF][0][ldsA], 16, 0, 0);  \
  __builtin_amdgcn_global_load_lds((const __attribute__((address_space(1))) void*)(Kh + _ba + 64 * DKK), \
      (__attribute__((address_space(3))) void*)&stB[BUF][0][2048 + ldsA], 16, 0, 0); \
  __builtin_amdgcn_global_load_lds((const __attribute__((address_space(1))) void*)(Kl + _ba), \
      (__attribute__((address_space(3))) void*)&stB[BUF][1][ldsA], 16, 0, 0);  \
  __builtin_amdgcn_global_load_lds((const __attribute__((address_space(1))) void*)(Kl + _ba + 64 * DKK), \
      (__attribute__((address_space(3))) void*)&stB[BUF][1][2048 + ldsA], 16, 0, 0); \
} while (0)

__global__ void __launch_bounds__(256, 2) gemm_topk_kernel(
    const _Float16* __restrict__ Qh, const _Float16* __restrict__ Ql,
    const _Float16* __restrict__ Kh, const _Float16* __restrict__ Kl,
    float* __restrict__ pscore, int* __restrict__ pidx) {
  __shared__ __attribute__((aligned(16))) _Float16 stA[2][2][BM * 32];  // 16 KB
  __shared__ __attribute__((aligned(16))) _Float16 stB[2][2][BN * 32];  // 32 KB
  __shared__ float topS[BM * 33];
  __shared__ int   topI[BM * 33];
  __shared__ float candS[BM * CSTR];
  __shared__ int   candI[BM * CSTR];
  __shared__ float mS[BM];
  __shared__ int   cnt[BM];
  __shared__ int   sOver;

  const int tid  = threadIdx.x;
  const int lane = tid & 63;
  const int w    = tid >> 6;
  const int wr   = w >> 1, wc = w & 1;   // wave tile 32x64
  const int cl   = lane & 15;
  const int g    = lane >> 4;
  const int g4   = g * 4;

  // XCD-chunked bijective swizzle: 1024 blocks = 8 XCD * 128; XCD x gets
  // splits [4x,4x+4) over all 32 M-blocks.
  const int lin   = (int)(blockIdx.x + gridDim.x * blockIdx.y);
  const int virt  = (lin & 7) * 128 + (lin >> 3);
  const int mblk  = virt & (MBLKS - 1);
  const int split = virt >> 5;
  const int qbase  = mblk * BM;
  const int nbase0 = split * NRANGE;

  // staging: thread t -> LDS elems [t*8, t*8+8) (linear); logical octet there
  // is pre-swizzled so reads can swizzle.
  const int soct = (tid & 3) ^ ((tid >> 3) & 3);
  const int ldsA = tid * 8;
  const size_t qsrc = (size_t)(qbase + (tid >> 2)) * DKK + (size_t)soct * 8;
  const size_t bsrc = (size_t)(tid >> 2) * DKK + (size_t)soct * 8;

  // fragment ds_read offsets (swizzled)
  int offA[2], offB[4];
#pragma unroll
  for (int mi = 0; mi < 2; ++mi) {
    const int r = wr * 32 + mi * 16 + cl;
    offA[mi] = r * 32 + (g ^ ((r >> 1) & 3)) * 8;
  }
#pragma unroll
  for (int ni = 0; ni < 4; ++ni) {
    const int c = wc * 64 + ni * 16 + cl;
    offB[ni] = c * 32 + (g ^ ((c >> 1) & 3)) * 8;
  }

  if (tid < BM) {
    mS[tid] = -INFINITY; cnt[tid] = 0;
#pragma unroll
    for (int j = 0; j < KTOP; ++j) { topS[tid*33+j] = -INFINITY; topI[tid*33+j] = 0x7fffffff; }
  }
  if (tid == 0) sOver = 0;

  STAGE(0, nbase0, 0);      // prologue
  __syncthreads();          // drains prologue gll (vmcnt 0) + topk init

  for (int ct = 0; ct < NTILES; ++ct) {
    const int n0 = nbase0 + ct * BN;
    f32x4 acc[2][4];
#pragma unroll
    for (int mi = 0; mi < 2; ++mi)
#pragma unroll
      for (int ni = 0; ni < 4; ++ni) acc[mi][ni] = (f32x4)0.0f;

#pragma unroll 2
    for (int ks = 0; ks < KSTEPS; ++ks) {
      const int cur = ks & 1;
      // T3 2-phase: issue next stage BEFORE this step's reads+MFMA
      if (ks < KSTEPS - 1)        { STAGE(cur ^ 1, n0, ks + 1); }
      else if (ct + 1 < NTILES)   { STAGE(cur ^ 1, n0 + BN, 0); }

      f16x8 Ah[2], Al[2], Bh[4], Bl[4];
#pragma unroll
      for (int mi = 0; mi < 2; ++mi) {
        Ah[mi] = *(const f16x8*)&stA[cur][0][offA[mi]];
        Al[mi] = *(const f16x8*)&stA[cur][1][offA[mi]];
      }
#pragma unroll
      for (int ni = 0; ni < 4; ++ni) {
        Bh[ni] = *(const f16x8*)&stB[cur][0][offB[ni]];
        Bl[ni] = *(const f16x8*)&stB[cur][1][offB[ni]];
      }
      // 3-term f16 split: S = AhBh + AhBl + AlBh (AlBl ~3e-9, dropped)
#pragma unroll
      for (int mi = 0; mi < 2; ++mi)
#pragma unroll
        for (int ni = 0; ni < 4; ++ni) {
          acc[mi][ni] = __builtin_amdgcn_mfma_f32_16x16x32_f16(Al[mi], Bh[ni], acc[mi][ni], 0, 0, 0);
          acc[mi][ni] = __builtin_amdgcn_mfma_f32_16x16x32_f16(Ah[mi], Bl[ni], acc[mi][ni], 0, 0, 0);
          acc[mi][ni] = __builtin_amdgcn_mfma_f32_16x16x32_f16(Ah[mi], Bh[ni], acc[mi][ni], 0, 0, 0);
        }
      __syncthreads();   // one barrier per K-step: drains gll + LDS reads
    }

    // -------- candidate scan from accumulators --------
    float m[2][4];
#pragma unroll
    for (int mi = 0; mi < 2; ++mi) {
      const f32x4 mv = *(const f32x4*)&mS[wr * 32 + mi * 16 + g4];
      m[mi][0] = mv[0]; m[mi][1] = mv[1]; m[mi][2] = mv[2]; m[mi][3] = mv[3];
    }
    unsigned int pend = 0u;
#pragma unroll
    for (int mi = 0; mi < 2; ++mi)
#pragma unroll
      for (int ni = 0; ni < 4; ++ni)
#pragma unroll
        for (int j = 0; j < 4; ++j)
          if (acc[mi][ni][j] >= m[mi][j])
            pend |= 1u << (mi * 16 + ni * 4 + j);

    for (;;) {
      if (pend) {
#pragma unroll
        for (int mi = 0; mi < 2; ++mi)
#pragma unroll
          for (int ni = 0; ni < 4; ++ni)
#pragma unroll
            for (int j = 0; j < 4; ++j) {
              const int bit = mi * 16 + ni * 4 + j;
              if (pend & (1u << bit)) {
                const int r = wr * 32 + mi * 16 + g4 + j;
                const int t = atomicAdd(&cnt[r], 1);
                if (t < CAP) {
                  candS[r * CSTR + t] = acc[mi][ni][j];
                  candI[r * CSTR + t] = n0 + wc * 64 + ni * 16 + cl;
                  pend &= ~(1u << bit);
                }
              }
            }
      }
      __syncthreads();
      if (tid < BM) {
        int nc = cnt[tid];
        if (nc > CAP) { sOver = 1; nc = CAP; }
        float* tS = &topS[tid * 33];
        int*   tI = &topI[tid * 33];
        for (int e = 0; e < nc; ++e) insert32(tS, tI, candS[tid * CSTR + e], candI[tid * CSTR + e]);
        mS[tid] = tS[KTOP - 1];
        cnt[tid] = 0;
      }
      __syncthreads();
      const int over = sOver;
      __syncthreads();
      if (tid == 0) sOver = 0;
      if (!over) break;
#pragma unroll
      for (int mi = 0; mi < 2; ++mi) {
        const f32x4 mv = *(const f32x4*)&mS[wr * 32 + mi * 16 + g4];
        m[mi][0] = mv[0]; m[mi][1] = mv[1]; m[mi][2] = mv[2]; m[mi][3] = mv[3];
      }
      unsigned int keep = 0u;
#pragma unroll
      for (int mi = 0; mi < 2; ++mi)
#pragma unroll
        for (int ni = 0; ni < 4; ++ni)
#pragma unroll
          for (int j = 0; j < 4; ++j) {
            const int bit = mi * 16 + ni * 4 + j;
            if ((pend & (1u << bit)) && acc[mi][ni][j] >= m[mi][j])
              keep |= 1u << bit;
          }
      pend = keep;
    }
  }

  if (tid < BM) {
    const size_t base = ((size_t)(qbase + tid) * NSPLIT + split) * KTOP;
    for (int j = 0; j < KTOP; ++j) {
      pscore[base + j] = topS[tid * 33 + j];
      pidx[base + j]   = topI[tid * 33 + j];
    }
  }
}

// ===================== FALLBACK (round-1, proven) =====================

#define QB 128
#define NB 128
#define KC 32
#define FNTILES (NRANGE / NB)
#define KCH (DKK / KC)
#define LDST 132

__global__ void __launch_bounds__(256) norm_kernel(
    const float* __restrict__ q, const float* __restrict__ keys,
    float* __restrict__ qn, float* __restrict__ kinv) {
  const int gw = (blockIdx.x * 256 + threadIdx.x) >> 6;
  const int lane = threadIdx.x & 63;
  if (gw < M_ROWS) {
    const float* row = q + (size_t)gw * DKK;
    float4 a = ((const float4*)row)[lane];
    float4 b = ((const float4*)row)[lane + 64];
    float s = a.x*a.x + a.y*a.y + a.z*a.z + a.w*a.w
            + b.x*b.x + b.y*b.y + b.z*b.z + b.w*b.w;
#pragma unroll
    for (int off = 32; off; off >>= 1) s += __shfl_xor(s, off);
    const float inv = 1.0f / fmaxf(sqrtf(s), 1e-12f);
    float* orow = qn + (size_t)gw * DKK;
    ((float4*)orow)[lane]      = make_float4(a.x*inv, a.y*inv, a.z*inv, a.w*inv);
    ((float4*)orow)[lane + 64] = make_float4(b.x*inv, b.y*inv, b.z*inv, b.w*inv);
  } else {
    const int n = gw - M_ROWS;
    if (n < N_KEYS) {
      const float* row = keys + (size_t)n * DKK;
      float4 a = ((const float4*)row)[lane];
      float4 b = ((const float4*)row)[lane + 64];
      float s = a.x*a.x + a.y*a.y + a.z*a.z + a.w*a.w
              + b.x*b.x + b.y*b.y + b.z*b.z + b.w*b.w;
#pragma unroll
      for (int off = 32; off; off >>= 1) s += __shfl_xor(s, off);
      if (lane == 0) kinv[n] = 1.0f / fmaxf(sqrtf(s), 1e-12f);
    }
  }
}

__device__ __forceinline__ void lds_wr_tile(float* dst, int k8, int r, float4 v, float scale) {
  dst[(k8 * 4 + 0) * LDST + r] = v.x * scale;
  dst[(k8 * 4 + 1) * LDST + r] = v.y * scale;
  dst[(k8 * 4 + 2) * LDST + r] = v.z * scale;
  dst[(k8 * 4 + 3) * LDST + r] = v.w * scale;
}

__global__ void __launch_bounds__(256, 1) score_topk_kernel(
    const float* __restrict__ qn, const float* __restrict__ keys,
    const float* __restrict__ kinv,
    float* __restrict__ pscore, int* __restrict__ pidx) {
  __shared__ float u[16896];
  __shared__ float topS[QB * KTOP];
  __shared__ int   topI[QB * KTOP];

  const int tid = threadIdx.x;
  const int tx = tid & 15, ty = tid >> 4;
  const int qbase = blockIdx.y * QB;
  const int nbase0 = blockIdx.x * NRANGE;

  for (int i = tid; i < QB * KTOP; i += 256) { topS[i] = -INFINITY; topI[i] = 0; }
  __syncthreads();

  for (int t = 0; t < FNTILES; ++t) {
    const int n0 = nbase0 + t * NB;
    float acc[8][8];
#pragma unroll
    for (int i = 0; i < 8; ++i)
#pragma unroll
      for (int j = 0; j < 8; ++j) acc[i][j] = 0.0f;

#pragma unroll
    for (int p = 0; p < 4; ++p) {
      const int id = tid + p * 256;
      const int r = id >> 3, k8 = id & 7;
      const float4 va = *(const float4*)&qn[(size_t)(qbase + r) * DKK + k8 * 4];
      const float4 vb = *(const float4*)&keys[(size_t)(n0 + r) * DKK + k8 * 4];
      const float kv = kinv[n0 + r];
      lds_wr_tile(u, k8, r, va, 1.0f);
      lds_wr_tile(u + 4224, k8, r, vb, kv);
    }
    __syncthreads();

    for (int kc = 0; kc < KCH; ++kc) {
      float4 pa[4], pb[4]; float pk[4];
      const bool pre = (kc + 1 < KCH);
      if (pre) {
#pragma unroll
        for (int p = 0; p < 4; ++p) {
          const int id = tid + p * 256;
          const int r = id >> 3, k8 = id & 7;
          pa[p] = *(const float4*)&qn[(size_t)(qbase + r) * DKK + (kc + 1) * KC + k8 * 4];
          pb[p] = *(const float4*)&keys[(size_t)(n0 + r) * DKK + (kc + 1) * KC + k8 * 4];
          pk[p] = kinv[n0 + r];
        }
      }
      const float* As = u + (kc & 1) * 8448;
      const float* Bs = As + 4224;
#pragma unroll 4
      for (int kk = 0; kk < KC; ++kk) {
        const float4 a0 = *(const float4*)&As[kk * LDST + ty * 4];
        const float4 a1 = *(const float4*)&As[kk * LDST + ty * 4 + 64];
        const float4 b0 = *(const float4*)&Bs[kk * LDST + tx * 4];
        const float4 b1 = *(const float4*)&Bs[kk * LDST + tx * 4 + 64];
        const float av[8] = {a0.x,a0.y,a0.z,a0.w,a1.x,a1.y,a1.z,a1.w};
        const float bv[8] = {b0.x,b0.y,b0.z,b0.w,b1.x,b1.y,b1.z,b1.w};
#pragma unroll
        for (int i = 0; i < 8; ++i)
#pragma unroll
          for (int j = 0; j < 8; ++j)
            acc[i][j] = fmaf(av[i], bv[j], acc[i][j]);
      }
      if (pre) {
        float* Ad = u + ((kc + 1) & 1) * 8448;
        float* Bd = Ad + 4224;
#pragma unroll
        for (int p = 0; p < 4; ++p) {
          const int id = tid + p * 256;
          const int r = id >> 3, k8 = id & 7;
          lds_wr_tile(Ad, k8, r, pa[p], 1.0f);
          lds_wr_tile(Bd, k8, r, pb[p], pk[p]);
        }
      }
      __syncthreads();
    }

#pragma unroll
    for (int ib = 0; ib < 2; ++ib)
#pragma unroll
      for (int i = 0; i < 4; ++i) {
        const int r = ty * 4 + i + ib * 64;
#pragma unroll
        for (int jb = 0; jb < 2; ++jb) {
          *(float4*)&u[r * LDST + tx * 4 + jb * 64] =
              make_float4(acc[ib*4+i][jb*4+0], acc[ib*4+i][jb*4+1],
                          acc[ib*4+i][jb*4+2], acc[ib*4+i][jb*4+3]);
        }
      }
    __syncthreads();

    if (tid < QB) {
      const int row = tid;
      float* tS = &topS[row * KTOP];
      int*   tI = &topI[row * KTOP];
      float mSv = tS[KTOP - 1]; int mIv = tI[KTOP - 1];
      for (int c4 = 0; c4 < NB / 4; ++c4) {
        const float4 v = *(const float4*)&u[row * LDST + c4 * 4];
#pragma unroll
        for (int wv = 0; wv < 4; ++wv) {
          const float s = (&v.x)[wv];
          const int idx = n0 + c4 * 4 + wv;
          if (s > mSv || (s == mSv && idx < mIv)) {
            int p = 0;
            while (p < KTOP && (tS[p] > s || (tS[p] == s && tI[p] < idx))) ++p;
            for (int qq = KTOP - 1; qq > p; --qq) { tS[qq] = tS[qq-1]; tI[qq] = tI[qq-1]; }
            tS[p] = s; tI[p] = idx;
            mSv = tS[KTOP - 1]; mIv = tI[KTOP - 1];
          }
        }
      }
    }
    __syncthreads();
  }

  if (tid < QB) {
    const size_t base = ((size_t)(qbase + tid) * NSPLIT + blockIdx.x) * KTOP;
    for (int j = 0; j < KTOP; ++j) {
      pscore[base + j] = topS[tid * KTOP + j];
      pidx[base + j]   = topI[tid * KTOP + j];
    }
  }
}

// ---------- shared: merge 32 sorted partial lists, softmax, gather ----------
__global__ void __launch_bounds__(256) merge_kernel(
    const float* __restrict__ pscore, const int* __restrict__ pidx,
    const float* __restrict__ values,
    float* __restrict__ out_agg, float* __restrict__ out_attn, float* __restrict__ out_idx) {
  __shared__ float attn_s[KTOP];
  __shared__ int   sel_i[KTOP];
  const int row = blockIdx.x;
  const int tid = threadIdx.x;

  if (tid < 64) {
    const int lane = tid;
    const float* ps = pscore + (size_t)row * NSPLIT * KTOP;
    const int*   pi = pidx   + (size_t)row * NSPLIT * KTOP;
    int pos = 0;
    float s; int idx;
    if (lane < NSPLIT) { s = ps[lane * KTOP]; idx = pi[lane * KTOP]; }
    else { s = -INFINITY; idx = 0x7fffffff; }
    for (int it = 0; it < KTOP; ++it) {
      float wsv = s; int wi = idx; int wl = lane;
#pragma unroll
      for (int off = 32; off; off >>= 1) {
        const float os = __shfl_xor(wsv, off);
        const int   oi = __shfl_xor(wi, off);
        const int   ol = __shfl_xor(wl, off);
        if (os > wsv || (os == wsv && oi < wi)) { wsv = os; wi = oi; wl = ol; }
      }
      if (lane == 0) { attn_s[it] = wsv; sel_i[it] = wi; }
      if (lane == wl) {
        ++pos;
        if (pos < KTOP) { s = ps[lane * KTOP + pos]; idx = pi[lane * KTOP + pos]; }
        else { s = -INFINITY; idx = 0x7fffffff; }
      }
    }
  }
  __syncthreads();
  if (tid < KTOP) {
    const float mm = attn_s[0];
    const float e = expf((attn_s[tid] - mm) * 10.0f);
    float tsum = e;
#pragma unroll
    for (int off = 16; off; off >>= 1) tsum += __shfl_xor(tsum, off);
    const float a = e / tsum;
    out_attn[(size_t)row * KTOP + tid] = a;
    out_idx [(size_t)row * KTOP + tid] = (float)sel_i[tid];
    attn_s[tid] = a;
  }
  __syncthreads();

  const int d = tid * 2;
  float2 accv = make_float2(0.0f, 0.0f);
  for (int j = 0; j < KTOP; ++j) {
    const float wgt = attn_s[j];
    const float2 v = *(const float2*)&values[(size_t)sel_i[j] * DVV + d];
    accv.x = fmaf(wgt, v.x, accv.x);
    accv.y = fmaf(wgt, v.y, accv.y);
  }
  *(float2*)&out_agg[(size_t)row * DVV + d] = accv;
}

extern "C" void kernel_launch(void* const* d_in, const int* in_sizes, int n_in,
                              void* d_out, int out_size, void* d_ws, size_t ws_size,
                              hipStream_t stream) {
  const float* q      = (const float*)d_in[0];
  const float* keys   = (const float*)d_in[1];
  const float* values = (const float*)d_in[2];

  float* out      = (float*)d_out;
  float* out_agg  = out;
  float* out_attn = out + (size_t)M_ROWS * DVV;
  float* out_idx  = out_attn + (size_t)M_ROWS * KTOP;

  const size_t needFast =
      (size_t)M_ROWS * DKK * 2 * 2
    + (size_t)N_KEYS * DKK * 2 * 2
    + (size_t)M_ROWS * NSPLIT * KTOP * 8;

  if (ws_size >= needFast) {
    _Float16* Qh = (_Float16*)d_ws;
    _Float16* Ql = Qh + (size_t)M_ROWS * DKK;
    _Float16* Kh = Ql + (size_t)M_ROWS * DKK;
    _Float16* Kl = Kh + (size_t)N_KEYS * DKK;
    float* pscore = (float*)(Kl + (size_t)N_KEYS * DKK);
    int*   pidx   = (int*)(pscore + (size_t)M_ROWS * NSPLIT * KTOP);

    norm_split_kernel<<<(M_ROWS + N_KEYS) / 4, 256, 0, stream>>>(q, keys, Qh, Ql, Kh, Kl);
    dim3 g2(MBLKS, NSPLIT, 1);
    gemm_topk_kernel<<<g2, 256, 0, stream>>>(Qh, Ql, Kh, Kl, pscore, pidx);
    merge_kernel<<<M_ROWS, 256, 0, stream>>>(pscore, pidx, values, out_agg, out_attn, out_idx);
  } else {
    float* ws     = (float*)d_ws;
    float* qn     = ws;
    float* kinv   = qn + (size_t)M_ROWS * DKK;
    float* pscore = kinv + N_KEYS;
    int*   pidx   = (int*)(pscore + (size_t)M_ROWS * NSPLIT * KTOP);

    norm_kernel<<<(M_ROWS + N_KEYS) / 4, 256, 0, stream>>>(q, keys, qn, kinv);
    dim3 g2(NSPLIT, M_ROWS / QB, 1);
    score_topk_kernel<<<g2, 256, 0, stream>>>(qn, keys, kinv, pscore, pidx);
    merge_kernel<<<M_ROWS, 256, 0, stream>>>(pscore, pidx, values, out_agg, out_attn, out_idx);
  }
}

// Round 6
// 1796.656 us; speedup vs baseline: 1.3194x; 1.3194x over previous
//
#include <hip/hip_runtime.h>
#include <math.h>

#define M_ROWS 2048
#define N_KEYS 65536
#define DKK 512
#define DVV 512
#define KTOP 32
#define NSPLIT 16
#define NRANGE (N_KEYS / NSPLIT)   // 4096
#define BM 128
#define BN 128
#define MBLKS (M_ROWS / BM)        // 16
#define NTILES (NRANGE / BN)       // 32
#define KSTEPS (DKK / 32)          // 16
#define TOT (NTILES * KSTEPS)      // 512
#define CAP 16
#define CSTR 17

typedef _Float16 f16x8 __attribute__((ext_vector_type(8)));
typedef _Float16 f16x4v __attribute__((ext_vector_type(4)));
typedef float f32x4 __attribute__((ext_vector_type(4)));

// ===================== FAST PATH =====================

__device__ __forceinline__ void split4(const float4 v, float inv,
                                       _Float16* ph, _Float16* pl) {
  f16x4v h, l;
  float y;
  y = v.x * inv; h[0] = (_Float16)y; l[0] = (_Float16)(y - (float)h[0]);
  y = v.y * inv; h[1] = (_Float16)y; l[1] = (_Float16)(y - (float)h[1]);
  y = v.z * inv; h[2] = (_Float16)y; l[2] = (_Float16)(y - (float)h[2]);
  y = v.w * inv; h[3] = (_Float16)y; l[3] = (_Float16)(y - (float)h[3]);
  *(f16x4v*)ph = h; *(f16x4v*)pl = l;
}

__global__ void __launch_bounds__(256) norm_split_kernel(
    const float* __restrict__ q, const float* __restrict__ keys,
    _Float16* __restrict__ Qh, _Float16* __restrict__ Ql,
    _Float16* __restrict__ Kh, _Float16* __restrict__ Kl) {
  const int gw = (blockIdx.x * 256 + threadIdx.x) >> 6;
  const int lane = threadIdx.x & 63;
  const float* row; _Float16 *oh, *ol;
  if (gw < M_ROWS) {
    row = q + (size_t)gw * DKK; oh = Qh + (size_t)gw * DKK; ol = Ql + (size_t)gw * DKK;
  } else {
    const int n = gw - M_ROWS;
    if (n >= N_KEYS) return;
    row = keys + (size_t)n * DKK; oh = Kh + (size_t)n * DKK; ol = Kl + (size_t)n * DKK;
  }
  const float4 a = ((const float4*)row)[lane];
  const float4 b = ((const float4*)row)[lane + 64];
  float s = a.x*a.x + a.y*a.y + a.z*a.z + a.w*a.w
          + b.x*b.x + b.y*b.y + b.z*b.z + b.w*b.w;
#pragma unroll
  for (int off = 32; off; off >>= 1) s += __shfl_xor(s, off);
  const float inv = 1.0f / fmaxf(sqrtf(s), 1e-12f);
  split4(a, inv, oh + lane * 4,       ol + lane * 4);
  split4(b, inv, oh + 256 + lane * 4, ol + 256 + lane * 4);
}

__device__ __forceinline__ void insert32(float* tS, int* tI, float s, int idx) {
  const float ms = tS[31]; const int mi_ = tI[31];
  if (s < ms || (s == ms && idx > mi_)) return;
  int p = 0;
  while (p < KTOP && (tS[p] > s || (tS[p] == s && tI[p] < idx))) ++p;
  for (int qq = KTOP - 1; qq > p; --qq) { tS[qq] = tS[qq-1]; tI[qq] = tI[qq-1]; }
  tS[p] = s; tI[p] = idx;
}

__device__ __forceinline__ void gll16(const _Float16* g, _Float16* l) {
  __builtin_amdgcn_global_load_lds(
      (const __attribute__((address_space(1))) void*)g,
      (__attribute__((address_space(3))) void*)l, 16, 0, 0);
}

// stage step S (buf B): A 128x32 (Qh,Ql) + B 128x32 (Kh,Kl), 4 gll/thread
#define STAGE(B, N0V, KOF) do {                                  \
  const size_t _qa = qsrc + (size_t)(KOF);                       \
  const size_t _ba = (size_t)(N0V) * DKK + bsrc + (size_t)(KOF); \
  gll16(Qh + _qa, &stA[B][0][ldsA]);                             \
  gll16(Ql + _qa, &stA[B][1][ldsA]);                             \
  gll16(Kh + _ba, &stB[B][0][ldsA]);                             \
  gll16(Kl + _ba, &stB[B][1][ldsA]);                             \
} while (0)

// K-step barrier: counted vmcnt (keep next stages in flight), raw s_barrier
#define KBAR(NVM) do {                                           \
  __builtin_amdgcn_sched_barrier(0);                             \
  asm volatile("s_waitcnt vmcnt(" #NVM ")" ::: "memory");        \
  __builtin_amdgcn_sched_barrier(0);                             \
  __builtin_amdgcn_s_barrier();                                  \
  __builtin_amdgcn_sched_barrier(0);                             \
} while (0)

// scan barrier: LDS-only drain, vmcnt untouched (stages keep flying)
#define LBAR() do {                                              \
  __builtin_amdgcn_sched_barrier(0);                             \
  asm volatile("s_waitcnt lgkmcnt(0)" ::: "memory");             \
  __builtin_amdgcn_sched_barrier(0);                             \
  __builtin_amdgcn_s_barrier();                                  \
  __builtin_amdgcn_sched_barrier(0);                             \
} while (0)

__global__ void __launch_bounds__(512, 2) gemm_topk_kernel(
    const _Float16* __restrict__ Qh, const _Float16* __restrict__ Ql,
    const _Float16* __restrict__ Kh, const _Float16* __restrict__ Kl,
    float* __restrict__ pscore, int* __restrict__ pidx) {
  __shared__ __attribute__((aligned(16))) _Float16 stA[3][2][BM * 32];  // 48 KB
  __shared__ __attribute__((aligned(16))) _Float16 stB[3][2][BN * 32];  // 48 KB
  __shared__ float topS[BM * 33];
  __shared__ int   topI[BM * 33];
  __shared__ float candS[BM * CSTR];
  __shared__ int   candI[BM * CSTR];
  __shared__ float mS[BM];
  __shared__ int   cnt[BM];
  __shared__ int   sOver;

  const int tid  = threadIdx.x;
  const int lane = tid & 63;
  const int w    = tid >> 6;           // 8 waves
  const int wr   = w >> 1, wc = w & 1; // wave tile 32x64 in 128x128
  const int cl   = lane & 15;
  const int g    = lane >> 4;
  const int g4   = g * 4;

  // XCD-chunked bijective swizzle: 256 blocks = 8 XCD * 32
  const int lin   = (int)(blockIdx.x + gridDim.x * blockIdx.y);
  const int virt  = (lin & 7) * 32 + (lin >> 3);
  const int mblk  = virt & (MBLKS - 1);
  const int split = virt >> 4;
  const int qbase  = mblk * BM;
  const int nbase0 = split * NRANGE;

  // staging: thread t covers (row = t>>2, swizzled octet) of a 128x32 tile
  const int soct = (tid & 3) ^ ((tid >> 3) & 3);
  const int ldsA = tid * 8;
  const size_t qsrc = (size_t)(qbase + (tid >> 2)) * DKK + (size_t)soct * 8;
  const size_t bsrc = (size_t)(tid >> 2) * DKK + (size_t)soct * 8;

  // fragment ds_read offsets (same XOR involution as the staged source)
  int offA[2], offB[4];
#pragma unroll
  for (int mi = 0; mi < 2; ++mi) {
    const int r = wr * 32 + mi * 16 + cl;
    offA[mi] = r * 32 + (g ^ ((r >> 1) & 3)) * 8;
  }
#pragma unroll
  for (int ni = 0; ni < 4; ++ni) {
    const int c = wc * 64 + ni * 16 + cl;
    offB[ni] = c * 32 + (g ^ ((c >> 1) & 3)) * 8;
  }

  if (tid < BM) {
    mS[tid] = -INFINITY; cnt[tid] = 0;
#pragma unroll
    for (int j = 0; j < KTOP; ++j) { topS[tid*33+j] = -INFINITY; topI[tid*33+j] = 0x7fffffff; }
  }
  if (tid == 0) sOver = 0;

  // prologue: stages 0 and 1 in flight (8 loads)
  STAGE(0, nbase0, 0);
  STAGE(1, nbase0, 32);

  int cur = 0;  // buffer holding the data for the current step

  for (int ct = 0; ct < NTILES; ++ct) {
    const int n0 = nbase0 + ct * BN;
    f32x4 acc[2][4];
#pragma unroll
    for (int mi = 0; mi < 2; ++mi)
#pragma unroll
      for (int ni = 0; ni < 4; ++ni) acc[mi][ni] = (f32x4)0.0f;

    for (int ks = 0; ks < KSTEPS; ++ks) {
      const int s = ct * KSTEPS + ks;
      // wait: oldest stage (this step's data) complete; next stage stays in flight
      if (s == TOT - 1) { KBAR(0); } else { KBAR(4); }

      // issue stage s+2 into the buffer freed at the previous barrier
      if (s + 2 < TOT) {
        int b2 = cur + 2; if (b2 >= 3) b2 -= 3;
        const int s2 = s + 2;
        const int ct2 = s2 >> 4, ks2 = s2 & 15;
        STAGE(b2, nbase0 + ct2 * BN, ks2 * 32);
      }

      f16x8 Ah[2], Al[2], Bh[4], Bl[4];
#pragma unroll
      for (int mi = 0; mi < 2; ++mi) {
        Ah[mi] = *(const f16x8*)&stA[cur][0][offA[mi]];
        Al[mi] = *(const f16x8*)&stA[cur][1][offA[mi]];
      }
#pragma unroll
      for (int ni = 0; ni < 4; ++ni) {
        Bh[ni] = *(const f16x8*)&stB[cur][0][offB[ni]];
        Bl[ni] = *(const f16x8*)&stB[cur][1][offB[ni]];
      }
      // 3-term f16 split: S = AhBh + AhBl + AlBh (AlBl ~3e-9, dropped)
      __builtin_amdgcn_s_setprio(1);
#pragma unroll
      for (int mi = 0; mi < 2; ++mi)
#pragma unroll
        for (int ni = 0; ni < 4; ++ni) {
          acc[mi][ni] = __builtin_amdgcn_mfma_f32_16x16x32_f16(Al[mi], Bh[ni], acc[mi][ni], 0, 0, 0);
          acc[mi][ni] = __builtin_amdgcn_mfma_f32_16x16x32_f16(Ah[mi], Bl[ni], acc[mi][ni], 0, 0, 0);
          acc[mi][ni] = __builtin_amdgcn_mfma_f32_16x16x32_f16(Ah[mi], Bh[ni], acc[mi][ni], 0, 0, 0);
        }
      __builtin_amdgcn_s_setprio(0);

      ++cur; if (cur >= 3) cur -= 3;
    }

    // -------- candidate scan from accumulators (vmcnt NOT drained) --------
    LBAR();   // MFMA regs final; protect cand/top LDS phases
    float m[2][4];
#pragma unroll
    for (int mi = 0; mi < 2; ++mi) {
      const f32x4 mv = *(const f32x4*)&mS[wr * 32 + mi * 16 + g4];
      m[mi][0] = mv[0]; m[mi][1] = mv[1]; m[mi][2] = mv[2]; m[mi][3] = mv[3];
    }
    unsigned int pend = 0u;
#pragma unroll
    for (int mi = 0; mi < 2; ++mi)
#pragma unroll
      for (int ni = 0; ni < 4; ++ni)
#pragma unroll
        for (int j = 0; j < 4; ++j)
          if (acc[mi][ni][j] >= m[mi][j])
            pend |= 1u << (mi * 16 + ni * 4 + j);

    for (;;) {
      if (pend) {
#pragma unroll
        for (int mi = 0; mi < 2; ++mi)
#pragma unroll
          for (int ni = 0; ni < 4; ++ni)
#pragma unroll
            for (int j = 0; j < 4; ++j) {
              const int bit = mi * 16 + ni * 4 + j;
              if (pend & (1u << bit)) {
                const int r = wr * 32 + mi * 16 + g4 + j;
                const int t = atomicAdd(&cnt[r], 1);
                if (t < CAP) {
                  candS[r * CSTR + t] = acc[mi][ni][j];
                  candI[r * CSTR + t] = n0 + wc * 64 + ni * 16 + cl;
                  pend &= ~(1u << bit);
                }
              }
            }
      }
      LBAR();
      if (tid < BM) {
        int nc = cnt[tid];
        if (nc > CAP) { sOver = 1; nc = CAP; }
        float* tS = &topS[tid * 33];
        int*   tI = &topI[tid * 33];
        for (int e = 0; e < nc; ++e) insert32(tS, tI, candS[tid * CSTR + e], candI[tid * CSTR + e]);
        mS[tid] = tS[KTOP - 1];
        cnt[tid] = 0;
      }
      LBAR();
      const int over = sOver;
      LBAR();
      if (tid == 0) sOver = 0;
      if (!over) break;
#pragma unroll
      for (int mi = 0; mi < 2; ++mi) {
        const f32x4 mv = *(const f32x4*)&mS[wr * 32 + mi * 16 + g4];
        m[mi][0] = mv[0]; m[mi][1] = mv[1]; m[mi][2] = mv[2]; m[mi][3] = mv[3];
      }
      unsigned int keep = 0u;
#pragma unroll
      for (int mi = 0; mi < 2; ++mi)
#pragma unroll
        for (int ni = 0; ni < 4; ++ni)
#pragma unroll
          for (int j = 0; j < 4; ++j) {
            const int bit = mi * 16 + ni * 4 + j;
            if ((pend & (1u << bit)) && acc[mi][ni][j] >= m[mi][j])
              keep |= 1u << bit;
          }
      pend = keep;
    }
  }

  if (tid < BM) {
    const size_t base = ((size_t)(qbase + tid) * NSPLIT + split) * KTOP;
    for (int j = 0; j < KTOP; ++j) {
      pscore[base + j] = topS[tid * 33 + j];
      pidx[base + j]   = topI[tid * 33 + j];
    }
  }
}

// ===================== FALLBACK (round-1, proven) =====================

#define QB 128
#define NB 128
#define KC 32
#define FNTILES (NRANGE / NB)
#define KCH (DKK / KC)
#define LDST 132

__global__ void __launch_bounds__(256) norm_kernel(
    const float* __restrict__ q, const float* __restrict__ keys,
    float* __restrict__ qn, float* __restrict__ kinv) {
  const int gw = (blockIdx.x * 256 + threadIdx.x) >> 6;
  const int lane = threadIdx.x & 63;
  if (gw < M_ROWS) {
    const float* row = q + (size_t)gw * DKK;
    float4 a = ((const float4*)row)[lane];
    float4 b = ((const float4*)row)[lane + 64];
    float s = a.x*a.x + a.y*a.y + a.z*a.z + a.w*a.w
            + b.x*b.x + b.y*b.y + b.z*b.z + b.w*b.w;
#pragma unroll
    for (int off = 32; off; off >>= 1) s += __shfl_xor(s, off);
    const float inv = 1.0f / fmaxf(sqrtf(s), 1e-12f);
    float* orow = qn + (size_t)gw * DKK;
    ((float4*)orow)[lane]      = make_float4(a.x*inv, a.y*inv, a.z*inv, a.w*inv);
    ((float4*)orow)[lane + 64] = make_float4(b.x*inv, b.y*inv, b.z*inv, b.w*inv);
  } else {
    const int n = gw - M_ROWS;
    if (n < N_KEYS) {
      const float* row = keys + (size_t)n * DKK;
      float4 a = ((const float4*)row)[lane];
      float4 b = ((const float4*)row)[lane + 64];
      float s = a.x*a.x + a.y*a.y + a.z*a.z + a.w*a.w
              + b.x*b.x + b.y*b.y + b.z*b.z + b.w*b.w;
#pragma unroll
      for (int off = 32; off; off >>= 1) s += __shfl_xor(s, off);
      if (lane == 0) kinv[n] = 1.0f / fmaxf(sqrtf(s), 1e-12f);
    }
  }
}

__device__ __forceinline__ void lds_wr_tile(float* dst, int k8, int r, float4 v, float scale) {
  dst[(k8 * 4 + 0) * LDST + r] = v.x * scale;
  dst[(k8 * 4 + 1) * LDST + r] = v.y * scale;
  dst[(k8 * 4 + 2) * LDST + r] = v.z * scale;
  dst[(k8 * 4 + 3) * LDST + r] = v.w * scale;
}

__global__ void __launch_bounds__(256, 1) score_topk_kernel(
    const float* __restrict__ qn, const float* __restrict__ keys,
    const float* __restrict__ kinv,
    float* __restrict__ pscore, int* __restrict__ pidx) {
  __shared__ float u[16896];
  __shared__ float topS[QB * KTOP];
  __shared__ int   topI[QB * KTOP];

  const int tid = threadIdx.x;
  const int tx = tid & 15, ty = tid >> 4;
  const int qbase = blockIdx.y * QB;
  const int nbase0 = blockIdx.x * NRANGE;

  for (int i = tid; i < QB * KTOP; i += 256) { topS[i] = -INFINITY; topI[i] = 0; }
  __syncthreads();

  for (int t = 0; t < FNTILES; ++t) {
    const int n0 = nbase0 + t * NB;
    float acc[8][8];
#pragma unroll
    for (int i = 0; i < 8; ++i)
#pragma unroll
      for (int j = 0; j < 8; ++j) acc[i][j] = 0.0f;

#pragma unroll
    for (int p = 0; p < 4; ++p) {
      const int id = tid + p * 256;
      const int r = id >> 3, k8 = id & 7;
      const float4 va = *(const float4*)&qn[(size_t)(qbase + r) * DKK + k8 * 4];
      const float4 vb = *(const float4*)&keys[(size_t)(n0 + r) * DKK + k8 * 4];
      const float kv = kinv[n0 + r];
      lds_wr_tile(u, k8, r, va, 1.0f);
      lds_wr_tile(u + 4224, k8, r, vb, kv);
    }
    __syncthreads();

    for (int kc = 0; kc < KCH; ++kc) {
      float4 pa[4], pb[4]; float pk[4];
      const bool pre = (kc + 1 < KCH);
      if (pre) {
#pragma unroll
        for (int p = 0; p < 4; ++p) {
          const int id = tid + p * 256;
          const int r = id >> 3, k8 = id & 7;
          pa[p] = *(const float4*)&qn[(size_t)(qbase + r) * DKK + (kc + 1) * KC + k8 * 4];
          pb[p] = *(const float4*)&keys[(size_t)(n0 + r) * DKK + (kc + 1) * KC + k8 * 4];
          pk[p] = kinv[n0 + r];
        }
      }
      const float* As = u + (kc & 1) * 8448;
      const float* Bs = As + 4224;
#pragma unroll 4
      for (int kk = 0; kk < KC; ++kk) {
        const float4 a0 = *(const float4*)&As[kk * LDST + ty * 4];
        const float4 a1 = *(const float4*)&As[kk * LDST + ty * 4 + 64];
        const float4 b0 = *(const float4*)&Bs[kk * LDST + tx * 4];
        const float4 b1 = *(const float4*)&Bs[kk * LDST + tx * 4 + 64];
        const float av[8] = {a0.x,a0.y,a0.z,a0.w,a1.x,a1.y,a1.z,a1.w};
        const float bv[8] = {b0.x,b0.y,b0.z,b0.w,b1.x,b1.y,b1.z,b1.w};
#pragma unroll
        for (int i = 0; i < 8; ++i)
#pragma unroll
          for (int j = 0; j < 8; ++j)
            acc[i][j] = fmaf(av[i], bv[j], acc[i][j]);
      }
      if (pre) {
        float* Ad = u + ((kc + 1) & 1) * 8448;
        float* Bd = Ad + 4224;
#pragma unroll
        for (int p = 0; p < 4; ++p) {
          const int id = tid + p * 256;
          const int r = id >> 3, k8 = id & 7;
          lds_wr_tile(Ad, k8, r, pa[p], 1.0f);
          lds_wr_tile(Bd, k8, r, pb[p], pk[p]);
        }
      }
      __syncthreads();
    }

#pragma unroll
    for (int ib = 0; ib < 2; ++ib)
#pragma unroll
      for (int i = 0; i < 4; ++i) {
        const int r = ty * 4 + i + ib * 64;
#pragma unroll
        for (int jb = 0; jb < 2; ++jb) {
          *(float4*)&u[r * LDST + tx * 4 + jb * 64] =
              make_float4(acc[ib*4+i][jb*4+0], acc[ib*4+i][jb*4+1],
                          acc[ib*4+i][jb*4+2], acc[ib*4+i][jb*4+3]);
        }
      }
    __syncthreads();

    if (tid < QB) {
      const int row = tid;
      float* tS = &topS[row * KTOP];
      int*   tI = &topI[row * KTOP];
      float mSv = tS[KTOP - 1]; int mIv = tI[KTOP - 1];
      for (int c4 = 0; c4 < NB / 4; ++c4) {
        const float4 v = *(const float4*)&u[row * LDST + c4 * 4];
#pragma unroll
        for (int wv = 0; wv < 4; ++wv) {
          const float s = (&v.x)[wv];
          const int idx = n0 + c4 * 4 + wv;
          if (s > mSv || (s == mSv && idx < mIv)) {
            int p = 0;
            while (p < KTOP && (tS[p] > s || (tS[p] == s && tI[p] < idx))) ++p;
            for (int qq = KTOP - 1; qq > p; --qq) { tS[qq] = tS[qq-1]; tI[qq] = tI[qq-1]; }
            tS[p] = s; tI[p] = idx;
            mSv = tS[KTOP - 1]; mIv = tI[KTOP - 1];
          }
        }
      }
    }
    __syncthreads();
  }

  if (tid < QB) {
    const size_t base = ((size_t)(qbase + tid) * NSPLIT + blockIdx.x) * KTOP;
    for (int j = 0; j < KTOP; ++j) {
      pscore[base + j] = topS[tid * KTOP + j];
      pidx[base + j]   = topI[tid * KTOP + j];
    }
  }
}

// ---------- shared: merge sorted partial lists, softmax, gather ----------
__global__ void __launch_bounds__(256) merge_kernel(
    const float* __restrict__ pscore, const int* __restrict__ pidx,
    const float* __restrict__ values,
    float* __restrict__ out_agg, float* __restrict__ out_attn, float* __restrict__ out_idx) {
  __shared__ float attn_s[KTOP];
  __shared__ int   sel_i[KTOP];
  const int row = blockIdx.x;
  const int tid = threadIdx.x;

  if (tid < 64) {
    const int lane = tid;
    const float* ps = pscore + (size_t)row * NSPLIT * KTOP;
    const int*   pi = pidx   + (size_t)row * NSPLIT * KTOP;
    int pos = 0;
    float s; int idx;
    if (lane < NSPLIT) { s = ps[lane * KTOP]; idx = pi[lane * KTOP]; }
    else { s = -INFINITY; idx = 0x7fffffff; }
    for (int it = 0; it < KTOP; ++it) {
      float wsv = s; int wi = idx; int wl = lane;
#pragma unroll
      for (int off = 32; off; off >>= 1) {
        const float os = __shfl_xor(wsv, off);
        const int   oi = __shfl_xor(wi, off);
        const int   ol = __shfl_xor(wl, off);
        if (os > wsv || (os == wsv && oi < wi)) { wsv = os; wi = oi; wl = ol; }
      }
      if (lane == 0) { attn_s[it] = wsv; sel_i[it] = wi; }
      if (lane == wl) {
        ++pos;
        if (pos < KTOP) { s = ps[lane * KTOP + pos]; idx = pi[lane * KTOP + pos]; }
        else { s = -INFINITY; idx = 0x7fffffff; }
      }
    }
  }
  __syncthreads();
  if (tid < KTOP) {
    const float mm = attn_s[0];
    const float e = expf((attn_s[tid] - mm) * 10.0f);
    float tsum = e;
#pragma unroll
    for (int off = 16; off; off >>= 1) tsum += __shfl_xor(tsum, off);
    const float a = e / tsum;
    out_attn[(size_t)row * KTOP + tid] = a;
    out_idx [(size_t)row * KTOP + tid] = (float)sel_i[tid];
    attn_s[tid] = a;
  }
  __syncthreads();

  const int d = tid * 2;
  float2 accv = make_float2(0.0f, 0.0f);
  for (int j = 0; j < KTOP; ++j) {
    const float wgt = attn_s[j];
    const float2 v = *(const float2*)&values[(size_t)sel_i[j] * DVV + d];
    accv.x = fmaf(wgt, v.x, accv.x);
    accv.y = fmaf(wgt, v.y, accv.y);
  }
  *(float2*)&out_agg[(size_t)row * DVV + d] = accv;
}

extern "C" void kernel_launch(void* const* d_in, const int* in_sizes, int n_in,
                              void* d_out, int out_size, void* d_ws, size_t ws_size,
                              hipStream_t stream) {
  const float* q      = (const float*)d_in[0];
  const float* keys   = (const float*)d_in[1];
  const float* values = (const float*)d_in[2];

  float* out      = (float*)d_out;
  float* out_agg  = out;
  float* out_attn = out + (size_t)M_ROWS * DVV;
  float* out_idx  = out_attn + (size_t)M_ROWS * KTOP;

  const size_t needFast =
      (size_t)M_ROWS * DKK * 2 * 2
    + (size_t)N_KEYS * DKK * 2 * 2
    + (size_t)M_ROWS * NSPLIT * KTOP * 8;

  if (ws_size >= needFast) {
    _Float16* Qh = (_Float16*)d_ws;
    _Float16* Ql = Qh + (size_t)M_ROWS * DKK;
    _Float16* Kh = Ql + (size_t)M_ROWS * DKK;
    _Float16* Kl = Kh + (size_t)N_KEYS * DKK;
    float* pscore = (float*)(Kl + (size_t)N_KEYS * DKK);
    int*   pidx   = (int*)(pscore + (size_t)M_ROWS * NSPLIT * KTOP);

    norm_split_kernel<<<(M_ROWS + N_KEYS) / 4, 256, 0, stream>>>(q, keys, Qh, Ql, Kh, Kl);
    dim3 g2(MBLKS, NSPLIT, 1);
    gemm_topk_kernel<<<g2, 512, 0, stream>>>(Qh, Ql, Kh, Kl, pscore, pidx);
    merge_kernel<<<M_ROWS, 256, 0, stream>>>(pscore, pidx, values, out_agg, out_attn, out_idx);
  } else {
    float* ws     = (float*)d_ws;
    float* qn     = ws;
    float* kinv   = qn + (size_t)M_ROWS * DKK;
    float* pscore = kinv + N_KEYS;
    int*   pidx   = (int*)(pscore + (size_t)M_ROWS * NSPLIT * KTOP);

    norm_kernel<<<(M_ROWS + N_KEYS) / 4, 256, 0, stream>>>(q, keys, qn, kinv);
    dim3 g2(NSPLIT, M_ROWS / QB, 1);
    score_topk_kernel<<<g2, 256, 0, stream>>>(qn, keys, kinv, pscore, pidx);
    merge_kernel<<<M_ROWS, 256, 0, stream>>>(pscore, pidx, values, out_agg, out_attn, out_idx);
  }
}